// Round 1
// baseline (120.686 us; speedup 1.0000x reference)
//
#include <hip/hip_runtime.h>
#include <hip/hip_bf16.h>
#include <math.h>

#define B_  4
#define R_  64
#define C_  192
#define WN_ 16

// B (weights) fragment-major: Wl[b][tap][kc][co][ci32] (bf16)
//   short index = (((b*9+tap)*6+kc)*192 + co)*32 + (ci%32)
// A (input): x pre-converted to bf16 in fragment order xbf16[b][h][kcl][px][ci32]
//   (kcl = ci/32 of the 6 32-channel chunks). conv stages it with
//   global_load_lds dwordx4 (no VALU, no reg round-trip), double-buffered
//   across the two kc-phases.

typedef __attribute__((ext_vector_type(8))) short short8;
typedef __attribute__((ext_vector_type(4))) float floatx4;

static __device__ __forceinline__ unsigned short f2bf(float f) {
    union { float f; unsigned u; } v; v.f = f;
    unsigned r = v.u + 0x7fffu + ((v.u >> 16) & 1u);
    return (unsigned short)(r >> 16);
}

static __device__ __forceinline__ void gload_lds16(const void* g, void* l) {
    __builtin_amdgcn_global_load_lds(
        (const __attribute__((address_space(1))) unsigned*)g,
        (__attribute__((address_space(3))) unsigned*)l, 16, 0, 0);
}

// ---------------------------------------------------------------------------
// Kernel 1: blocks [0,256) = pool partials (one quarter-window each),
// blocks [256,310) = conv1_w transpose to cw_t[tap][win][ci],
// blocks [310,566) = x fp32 -> bf16 fragment-order copy (one (b,h) row each).
// ---------------------------------------------------------------------------
__global__ __launch_bounds__(256) void pre_kernel(
        const float* __restrict__ x,
        const float* __restrict__ conv1_w,
        const float* __restrict__ dc_w,
        float* __restrict__ w0p,
        float* __restrict__ cw_t,
        unsigned short* __restrict__ xbf16) {
    __shared__ float part[3];
    int blk = blockIdx.x;
    int tid = threadIdx.x;

    if (blk < 256) {
        int b = blk >> 6, rest = blk & 63, win = rest >> 2, q = rest & 3;
        int wr = win >> 2, wc = win & 3;
        if (tid < 192) {
            const float* xb = x + ((size_t)b * 4096) * C_ + tid;
            float Wsum = 0.f, Rtop = 0.f, Rbot = 0.f, Cleft = 0.f, Cright = 0.f;
            float c00 = 0.f, c0F = 0.f, cF0 = 0.f, cFF = 0.f;
            #pragma unroll
            for (int pr = 0; pr < 4; ++pr) {
                int h = wr * 16 + q * 4 + pr;
                #pragma unroll
                for (int pw = 0; pw < 16; ++pw) {
                    int w = wc * 16 + pw;
                    float v = xb[(size_t)(h * 64 + w) * C_];
                    Wsum += v;
                    if (q == 0 && pr == 0) { Rtop += v; if (pw == 0) c00 = v; if (pw == 15) c0F = v; }
                    if (q == 3 && pr == 3) { Rbot += v; if (pw == 0) cF0 = v; if (pw == 15) cFF = v; }
                    if (pw == 0)  Cleft  += v;
                    if (pw == 15) Cright += v;
                }
            }
            const float* kp = conv1_w + ((size_t)(win * C_ + tid)) * 9;
            float pooled = 0.f;
            #pragma unroll
            for (int i = 0; i < 3; ++i) {
                #pragma unroll
                for (int j = 0; j < 3; ++j) {
                    int di = i - 1, dj = j - 1;
                    float S = Wsum;
                    if (di == -1) S -= Rbot;   else if (di == 1) S -= Rtop;
                    if (dj == -1) S -= Cright; else if (dj == 1) S -= Cleft;
                    if (di == -1 && dj == -1) S += cFF;
                    if (di == -1 && dj ==  1) S += cF0;
                    if (di ==  1 && dj == -1) S += c0F;
                    if (di ==  1 && dj ==  1) S += c00;
                    pooled += kp[i * 3 + j] * S;
                }
            }
            float val = (pooled * (1.f / 256.f)) * dc_w[win * C_ + tid];
            for (int off = 32; off; off >>= 1) val += __shfl_down(val, off, 64);
            if ((tid & 63) == 0) part[tid >> 6] = val;
        }
        __syncthreads();
        if (tid == 0) w0p[blk] = part[0] + part[1] + part[2];
    } else if (blk < 310) {
        int basei = (blk - 256) * 512 + tid * 2;   // 54*512 = 27648 elements
        #pragma unroll
        for (int e = 0; e < 2; ++e) {
            int o = basei + e;
            int t = o / 3072;
            int r = o - t * 3072;                  // win*192+ci
            cw_t[o] = conv1_w[(size_t)r * 9 + t];
        }
    } else {
        // x -> bf16 fragment layout: one (b,h) row of 64 px x 192 ch.
        // dst plane = 6 kcl x 64 px x 32 ci = 12288 shorts, contiguous.
        int m = blk - 310;
        int b = m >> 6, hh = m & 63;
        const float* src = x + ((size_t)(b * 4096 + hh * 64)) * C_;
        unsigned short* dst = xbf16 + ((size_t)(b * 64 + hh)) * 12288;
        int px = tid >> 2, c4 = (tid & 3) * 8;
        #pragma unroll
        for (int j = 0; j < 6; ++j) {            // j == kcl
            const float* p = src + (size_t)px * C_ + j * 32 + c4;
            float4 v0 = *(const float4*)p;
            float4 v1 = *(const float4*)(p + 4);
            short8 o;
            o[0] = (short)f2bf(v0.x); o[1] = (short)f2bf(v0.y);
            o[2] = (short)f2bf(v0.z); o[3] = (short)f2bf(v0.w);
            o[4] = (short)f2bf(v1.x); o[5] = (short)f2bf(v1.y);
            o[6] = (short)f2bf(v1.z); o[7] = (short)f2bf(v1.w);
            *(short8*)(dst + j * 2048 + px * 32 + c4) = o;
        }
    }
}

// ---------------------------------------------------------------------------
// Kernel 2: gates (tiny MLP, redundant per block) + effective dense conv
// weights in fragment-major bf16 layout Wl[b][tap][kc][co][ci32].
// ---------------------------------------------------------------------------
__global__ __launch_bounds__(192) void weff_kernel(
        const float* __restrict__ cw_t,
        const float* __restrict__ gk_w,
        const float* __restrict__ gk_b,
        const float* __restrict__ fusion_w,
        const float* __restrict__ w0p,
        const float* __restrict__ dc_b,
        const float* __restrict__ l1_w,
        const float* __restrict__ l1_b,
        const float* __restrict__ l2_w,
        const float* __restrict__ l2_b,
        unsigned short* __restrict__ Wl) {
    __shared__ float hbuf[64];
    __shared__ float s_sh[16];
    int blk = blockIdx.x;             // b*192 + co
    int b = blk / C_, co = blk % C_;
    int tid = threadIdx.x;            // 0..191

    if (tid < 64) {
        float a = l1_b[tid];
        #pragma unroll
        for (int w = 0; w < 16; ++w) {
            float w0 = w0p[b * 64 + w * 4 + 0] + w0p[b * 64 + w * 4 + 1]
                     + w0p[b * 64 + w * 4 + 2] + w0p[b * 64 + w * 4 + 3];
            a += (w0 + dc_b[w]) * l1_w[tid * 16 + w];
        }
        hbuf[tid] = 0.5f * a * (1.f + erff(a * 0.70710678118654752f));
    }
    __syncthreads();
    if (tid < 16) {
        float a2 = l2_b[tid];
        #pragma unroll
        for (int k = 0; k < 64; ++k) a2 += hbuf[k] * l2_w[tid * 64 + k];
        s_sh[tid] = 1.f / (1.f + expf(-a2));
    }
    __syncthreads();

    int ci = tid;
    float fg = fusion_w[(size_t)co * 3264 + 16 * C_ + ci];
    float acc[9];
    float g0 = fg * gk_b[0];
    #pragma unroll
    for (int t = 0; t < 9; ++t) acc[t] = g0;
    for (int w = 0; w < 16; ++w) {
        float coef = (fusion_w[(size_t)co * 3264 + w * C_ + ci] + fg * gk_w[w]) * s_sh[w];
        #pragma unroll
        for (int t = 0; t < 9; ++t)
            acc[t] += coef * cw_t[t * 3072 + w * C_ + ci];
    }
    #pragma unroll
    for (int t = 0; t < 9; ++t) {
        int kc = ci >> 5, cio = ci & 31;
        Wl[((((size_t)(b * 9 + t)) * 6 + kc) * C_ + co) * 32 + cio] = f2bf(acc[t]);
    }
}

// ---------------------------------------------------------------------------
// Kernel 3 (v4): dense 3x3 conv, implicit GEMM. 256 threads = 4 waves; block
// = one row (M=64px) x 192 co. Wave = 64px x 48co: m=4 x n=3 -> 12 MFMA per
// (4 LDS-A + 3 global-B) loads. A now staged from pre-converted bf16 via
// global_load_lds dwordx4 (no VALU convert, no reg round-trip, half the
// bytes), DOUBLE-BUFFERED across the two kc-phases so phase-1 staging is in
// flight under phase-0's 27 K-steps (only drained by the inter-phase
// barrier). Halo columns/rows zeroed once at start (loads never touch them).
// LDS 2 x 19,008 shorts = 76,032 B. Grid 256 = 1 block/CU; XCD swizzle: 2
// XCDs per batch -> Wl slice 663 KB resident in each L2.
// ---------------------------------------------------------------------------
__global__ __launch_bounds__(256, 1) void conv_kernel(
        const unsigned short* __restrict__ xbf16,
        const unsigned short* __restrict__ Wl,
        const float* __restrict__ fusion_b,
        float* __restrict__ out) {
    __shared__ unsigned short Asm[2 * 3 * 3 * 66 * 32];   // 76,032 B
    const int n = blockIdx.x;
    const int g = (n & 7) * 32 + (n >> 3);
    const int b = g >> 6, h = g & 63;
    const int tid = threadIdx.x;
    const int wv = tid >> 6, lane = tid & 63;
    const int lo = lane & 15, quad = lane >> 4;
    const int n0 = wv * 48;

    const short* wp = (const short*)Wl;
    int Bbase[3];
    #pragma unroll
    for (int nt = 0; nt < 3; ++nt)
        Bbase[nt] = (b * 54 * C_ + n0 + nt * 16 + lo) * 32 + quad * 8;
    int Alds[4];
    #pragma unroll
    for (int mt = 0; mt < 4; ++mt)
        Alds[mt] = (mt * 16 + lo + 1) * 32 + quad * 8;

    floatx4 acc[4][3];
    #pragma unroll
    for (int mt = 0; mt < 4; ++mt)
        #pragma unroll
        for (int nt = 0; nt < 3; ++nt)
            acc[mt][nt] = (floatx4){0.f, 0.f, 0.f, 0.f};

    // ---- zero both LDS buffers once (halo px=0/65 + out-of-range rows stay 0)
    for (int c = tid; c < 4752; c += 256)
        *(short8*)(Asm + c * 8) = (short8){0, 0, 0, 0, 0, 0, 0, 0};
    __syncthreads();

    // ---- async stage: 36 chunks of 1 KB per phase (3 rows x 3 kcl x 4
    // quarters), 9 gload_lds per wave. dst is wave-uniform; lane l lands at
    // dst + l*16 -> px = 1 + q*16 + l/4, ci0 = (l%4)*8, matching xbf16 order.
    auto issue_phase = [&](int buf, int ph) {
        const int kc0 = ph * 3;
        #pragma unroll
        for (int i = 0; i < 9; ++i) {
            int c = wv * 9 + i;
            int r = c / 12, kcl = (c % 12) >> 2, q = c & 3;
            int hr = h - 1 + r;
            if (hr >= 0 && hr < 64) {
                const unsigned short* src = xbf16
                    + ((((size_t)(b * 64 + hr)) * 6 + (kc0 + kcl)) << 11)
                    + (q << 9) + lane * 8;
                unsigned short* dst = Asm + buf * 19008
                    + ((r * 3 + kcl) * 66 + 1) * 32 + q * 512;
                gload_lds16(src, dst);
            }
        }
    };

    issue_phase(0, 0);
    __syncthreads();            // vmcnt(0) drain -> buf0 ready
    issue_phase(1, 1);          // in flight under phase-0 compute

    #pragma unroll
    for (int ph = 0; ph < 2; ++ph) {
        const int kc0 = ph * 3;
        const unsigned short* As = Asm + ph * 19008;

        // ---- 27 K-steps: taps 0..8 x kcl 0..2
        short8 Bb[3][3], Ab[2][4];
        auto loadB = [&](int t27, int slot) {
            int tap = t27 / 3, kcl = t27 % 3;
            int s = tap * 6 + kc0 + kcl;
            #pragma unroll
            for (int nt = 0; nt < 3; ++nt)
                Bb[slot][nt] = *(const short8*)(wp + Bbase[nt] + s * (C_ * 32));
        };
        auto loadA = [&](int t27, int slot) {
            int tap = t27 / 3, kcl = t27 % 3;
            int dh = tap / 3, dw = tap % 3 - 1;
            int base = ((dh * 3 + kcl) * 66 + dw) * 32;
            #pragma unroll
            for (int mt = 0; mt < 4; ++mt)
                Ab[slot][mt] = *(const short8*)((const short*)As + base + Alds[mt]);
        };
        loadB(0, 0); loadB(1, 1); loadA(0, 0);
        #pragma unroll
        for (int t = 0; t < 27; ++t) {
            const int bc = t % 3, ac = t & 1;
            if (t + 2 < 27) loadB(t + 2, (t + 2) % 3);
            if (t + 1 < 27) loadA(t + 1, ac ^ 1);
            #pragma unroll
            for (int mt = 0; mt < 4; ++mt)
                #pragma unroll
                for (int nt = 0; nt < 3; ++nt)
                    acc[mt][nt] = __builtin_amdgcn_mfma_f32_16x16x32_bf16(
                        Ab[ac][mt], Bb[bc][nt], acc[mt][nt], 0, 0, 0);
        }
        if (ph == 0)
            __syncthreads();    // vmcnt(0) drain -> buf1 ready
    }

    // ---- epilogue
    #pragma unroll
    for (int nt = 0; nt < 3; ++nt) {
        const int co = n0 + nt * 16 + lo;
        const float fb = fusion_b[co];
        #pragma unroll
        for (int mt = 0; mt < 4; ++mt) {
            #pragma unroll
            for (int r = 0; r < 4; ++r) {
                const int px = mt * 16 + quad * 4 + r;
                out[((size_t)(b * 4096 + h * 64 + px)) * C_ + co] = acc[mt][nt][r] + fb;
            }
        }
    }
}

// ---------------------------------------------------------------------------
extern "C" void kernel_launch(void* const* d_in, const int* in_sizes, int n_in,
                              void* d_out, int out_size, void* d_ws, size_t ws_size,
                              hipStream_t stream) {
    const float* x        = (const float*)d_in[0];
    const float* conv1_w  = (const float*)d_in[1];
    const float* dc_w     = (const float*)d_in[2];
    const float* dc_b     = (const float*)d_in[3];
    const float* l1_w     = (const float*)d_in[4];
    const float* l1_b     = (const float*)d_in[5];
    const float* l2_w     = (const float*)d_in[6];
    const float* l2_b     = (const float*)d_in[7];
    const float* gk_w     = (const float*)d_in[8];
    const float* gk_b     = (const float*)d_in[9];
    const float* fusion_w = (const float*)d_in[10];
    const float* fusion_b = (const float*)d_in[11];
    float* out = (float*)d_out;

    char* ws = (char*)d_ws;
    float* w0p  = (float*)ws;                                   // 1,024 B
    float* cw_t = (float*)(ws + 1024);                          // 110,592 B
    unsigned short* Wl = (unsigned short*)(ws + 1024 + 110592); // 2,654,208 B
    unsigned short* xbf16 = (unsigned short*)(ws + 1024 + 110592 + 2654208); // 6,291,456 B

    hipLaunchKernelGGL(pre_kernel, dim3(566), dim3(256), 0, stream,
                       x, conv1_w, dc_w, w0p, cw_t, xbf16);
    hipLaunchKernelGGL(weff_kernel, dim3(B_ * C_), dim3(192), 0, stream,
                       cw_t, gk_w, gk_b, fusion_w, w0p, dc_b, l1_w, l1_b, l2_w, l2_b, Wl);
    hipLaunchKernelGGL(conv_kernel, dim3(256), dim3(256), 0, stream,
                       xbf16, Wl, fusion_b, out);
}

// Round 2
// 117.545 us; speedup vs baseline: 1.0267x; 1.0267x over previous
//
#include <hip/hip_runtime.h>
#include <hip/hip_bf16.h>
#include <math.h>

#define B_  4
#define R_  64
#define C_  192
#define WN_ 16

// B (weights) fragment-major: Wl[b][tap][kc][co][ci32] (bf16)
//   short index = (((b*9+tap)*6+kc)*192 + co)*32 + (ci%32)
// A (input): x pre-converted to bf16 in fragment order xbf16[b][h][kcl][px][ci32]
//   (kcl = ci/32 of the 6 32-channel chunks). conv stages it with
//   global_load_lds dwordx4, double-buffered across the two kc-phases.

typedef __attribute__((ext_vector_type(8))) short short8;
typedef __attribute__((ext_vector_type(4))) float floatx4;

static __device__ __forceinline__ unsigned short f2bf(float f) {
    union { float f; unsigned u; } v; v.f = f;
    unsigned r = v.u + 0x7fffu + ((v.u >> 16) & 1u);
    return (unsigned short)(r >> 16);
}

static __device__ __forceinline__ void gload_lds16(const void* g, void* l) {
    __builtin_amdgcn_global_load_lds(
        (const __attribute__((address_space(1))) unsigned*)g,
        (__attribute__((address_space(3))) unsigned*)l, 16, 0, 0);
}

// ---------------------------------------------------------------------------
// Kernel 1: blocks [0,256) = pool partials (one quarter-window each),
// blocks [256,310) = conv1_w transpose to cw_t[tap][win][ci],
// blocks [310,566) = x fp32 -> bf16 fragment-order copy (one (b,h) row each).
// ---------------------------------------------------------------------------
__global__ __launch_bounds__(256) void pre_kernel(
        const float* __restrict__ x,
        const float* __restrict__ conv1_w,
        const float* __restrict__ dc_w,
        float* __restrict__ w0p,
        float* __restrict__ cw_t,
        unsigned short* __restrict__ xbf16) {
    __shared__ float part[3];
    int blk = blockIdx.x;
    int tid = threadIdx.x;

    if (blk < 256) {
        int b = blk >> 6, rest = blk & 63, win = rest >> 2, q = rest & 3;
        int wr = win >> 2, wc = win & 3;
        if (tid < 192) {
            const float* xb = x + ((size_t)b * 4096) * C_ + tid;
            float Wsum = 0.f, Rtop = 0.f, Rbot = 0.f, Cleft = 0.f, Cright = 0.f;
            float c00 = 0.f, c0F = 0.f, cF0 = 0.f, cFF = 0.f;
            #pragma unroll
            for (int pr = 0; pr < 4; ++pr) {
                int h = wr * 16 + q * 4 + pr;
                #pragma unroll
                for (int pw = 0; pw < 16; ++pw) {
                    int w = wc * 16 + pw;
                    float v = xb[(size_t)(h * 64 + w) * C_];
                    Wsum += v;
                    if (q == 0 && pr == 0) { Rtop += v; if (pw == 0) c00 = v; if (pw == 15) c0F = v; }
                    if (q == 3 && pr == 3) { Rbot += v; if (pw == 0) cF0 = v; if (pw == 15) cFF = v; }
                    if (pw == 0)  Cleft  += v;
                    if (pw == 15) Cright += v;
                }
            }
            const float* kp = conv1_w + ((size_t)(win * C_ + tid)) * 9;
            float pooled = 0.f;
            #pragma unroll
            for (int i = 0; i < 3; ++i) {
                #pragma unroll
                for (int j = 0; j < 3; ++j) {
                    int di = i - 1, dj = j - 1;
                    float S = Wsum;
                    if (di == -1) S -= Rbot;   else if (di == 1) S -= Rtop;
                    if (dj == -1) S -= Cright; else if (dj == 1) S -= Cleft;
                    if (di == -1 && dj == -1) S += cFF;
                    if (di == -1 && dj ==  1) S += cF0;
                    if (di ==  1 && dj == -1) S += c0F;
                    if (di ==  1 && dj ==  1) S += c00;
                    pooled += kp[i * 3 + j] * S;
                }
            }
            float val = (pooled * (1.f / 256.f)) * dc_w[win * C_ + tid];
            for (int off = 32; off; off >>= 1) val += __shfl_down(val, off, 64);
            if ((tid & 63) == 0) part[tid >> 6] = val;
        }
        __syncthreads();
        if (tid == 0) w0p[blk] = part[0] + part[1] + part[2];
    } else if (blk < 310) {
        int basei = (blk - 256) * 512 + tid * 2;   // 54*512 = 27648 elements
        #pragma unroll
        for (int e = 0; e < 2; ++e) {
            int o = basei + e;
            int t = o / 3072;
            int r = o - t * 3072;                  // win*192+ci
            cw_t[o] = conv1_w[(size_t)r * 9 + t];
        }
    } else {
        // x -> bf16 fragment layout: one (b,h) row of 64 px x 192 ch.
        // dst plane = 6 kcl x 64 px x 32 ci = 12288 shorts, contiguous.
        int m = blk - 310;
        int b = m >> 6, hh = m & 63;
        const float* src = x + ((size_t)(b * 4096 + hh * 64)) * C_;
        unsigned short* dst = xbf16 + ((size_t)(b * 64 + hh)) * 12288;
        int px = tid >> 2, c4 = (tid & 3) * 8;
        #pragma unroll
        for (int j = 0; j < 6; ++j) {            // j == kcl
            const float* p = src + (size_t)px * C_ + j * 32 + c4;
            float4 v0 = *(const float4*)p;
            float4 v1 = *(const float4*)(p + 4);
            short8 o;
            o[0] = (short)f2bf(v0.x); o[1] = (short)f2bf(v0.y);
            o[2] = (short)f2bf(v0.z); o[3] = (short)f2bf(v0.w);
            o[4] = (short)f2bf(v1.x); o[5] = (short)f2bf(v1.y);
            o[6] = (short)f2bf(v1.z); o[7] = (short)f2bf(v1.w);
            *(short8*)(dst + j * 2048 + px * 32 + c4) = o;
        }
    }
}

// ---------------------------------------------------------------------------
// Kernel 2: gates (tiny MLP, redundant per block) + effective dense conv
// weights in fragment-major bf16 layout Wl[b][tap][kc][co][ci32].
// ---------------------------------------------------------------------------
__global__ __launch_bounds__(192) void weff_kernel(
        const float* __restrict__ cw_t,
        const float* __restrict__ gk_w,
        const float* __restrict__ gk_b,
        const float* __restrict__ fusion_w,
        const float* __restrict__ w0p,
        const float* __restrict__ dc_b,
        const float* __restrict__ l1_w,
        const float* __restrict__ l1_b,
        const float* __restrict__ l2_w,
        const float* __restrict__ l2_b,
        unsigned short* __restrict__ Wl) {
    __shared__ float hbuf[64];
    __shared__ float s_sh[16];
    int blk = blockIdx.x;             // b*192 + co
    int b = blk / C_, co = blk % C_;
    int tid = threadIdx.x;            // 0..191

    if (tid < 64) {
        float a = l1_b[tid];
        #pragma unroll
        for (int w = 0; w < 16; ++w) {
            float w0 = w0p[b * 64 + w * 4 + 0] + w0p[b * 64 + w * 4 + 1]
                     + w0p[b * 64 + w * 4 + 2] + w0p[b * 64 + w * 4 + 3];
            a += (w0 + dc_b[w]) * l1_w[tid * 16 + w];
        }
        hbuf[tid] = 0.5f * a * (1.f + erff(a * 0.70710678118654752f));
    }
    __syncthreads();
    if (tid < 16) {
        float a2 = l2_b[tid];
        #pragma unroll
        for (int k = 0; k < 64; ++k) a2 += hbuf[k] * l2_w[tid * 64 + k];
        s_sh[tid] = 1.f / (1.f + expf(-a2));
    }
    __syncthreads();

    int ci = tid;
    float fg = fusion_w[(size_t)co * 3264 + 16 * C_ + ci];
    float acc[9];
    float g0 = fg * gk_b[0];
    #pragma unroll
    for (int t = 0; t < 9; ++t) acc[t] = g0;
    for (int w = 0; w < 16; ++w) {
        float coef = (fusion_w[(size_t)co * 3264 + w * C_ + ci] + fg * gk_w[w]) * s_sh[w];
        #pragma unroll
        for (int t = 0; t < 9; ++t)
            acc[t] += coef * cw_t[t * 3072 + w * C_ + ci];
    }
    #pragma unroll
    for (int t = 0; t < 9; ++t) {
        int kc = ci >> 5, cio = ci & 31;
        Wl[((((size_t)(b * 9 + t)) * 6 + kc) * C_ + co) * 32 + cio] = f2bf(acc[t]);
    }
}

// ---------------------------------------------------------------------------
// Kernel 3 (v5): dense 3x3 conv, implicit GEMM. 256 threads = 4 waves; block
// = one row (M=64px) x 192 co. Wave = 64px x 48co: m=4 x n=3 -> 12 MFMA per
// step. Changes vs v4: B ring depth 5 / issue 4 ahead (covers ~230cyc > L2
// ~200cyc latency; depth-2 only covered 116cyc and 1 wave/SIMD has no TLP to
// hide the rest); A ring depth 3 / issue 2 ahead (covers ds_read ~120cyc);
// phase-1's first 4 B loads pre-issued before the inter-phase barrier;
// staging issued before B prologue so both latencies share the first drain;
// LDS zeroing reduced to halo columns for interior blocks. VGPR ~180, still
// 1 block/CU; XCD swizzle keeps each batch's 663 KB Wl slice L2-resident.
// ---------------------------------------------------------------------------
__global__ __launch_bounds__(256, 1) void conv_kernel(
        const unsigned short* __restrict__ xbf16,
        const unsigned short* __restrict__ Wl,
        const float* __restrict__ fusion_b,
        float* __restrict__ out) {
    __shared__ unsigned short Asm[2 * 3 * 3 * 66 * 32];   // 76,032 B
    const int n = blockIdx.x;
    const int g = (n & 7) * 32 + (n >> 3);
    const int b = g >> 6, h = g & 63;
    const int tid = threadIdx.x;
    const int wv = tid >> 6, lane = tid & 63;
    const int lo = lane & 15, quad = lane >> 4;
    const int n0 = wv * 48;

    const short* wp = (const short*)Wl;
    int Bbase[3];
    #pragma unroll
    for (int nt = 0; nt < 3; ++nt)
        Bbase[nt] = (b * 54 * C_ + n0 + nt * 16 + lo) * 32 + quad * 8;
    int Alds[4];
    #pragma unroll
    for (int mt = 0; mt < 4; ++mt)
        Alds[mt] = (mt * 16 + lo + 1) * 32 + quad * 8;

    floatx4 acc[4][3];
    #pragma unroll
    for (int mt = 0; mt < 4; ++mt)
        #pragma unroll
        for (int nt = 0; nt < 3; ++nt)
            acc[mt][nt] = (floatx4){0.f, 0.f, 0.f, 0.f};

    // ---- zero LDS: full slabs only for boundary rows (their missing-row
    // slab is never staged); interior blocks just need the px=0/65 halo
    // columns (gload_lds covers px 1..64 fully each phase).
    const short8 z8 = {0, 0, 0, 0, 0, 0, 0, 0};
    if (h == 0 || h == 63) {
        for (int c = tid; c < 4752; c += 256)
            *(short8*)(Asm + c * 8) = z8;
    } else if (tid < 144) {
        int buf = tid / 72, u = tid % 72;
        int loc = u >> 2, j = u & 3;
        int r = loc / 6, rem = loc % 6, kcl = rem >> 1, px = (rem & 1) * 65;
        *(short8*)(Asm + buf * 19008 + ((r * 3 + kcl) * 66 + px) * 32 + j * 8) = z8;
    }
    __syncthreads();

    // ---- async stage: 36 chunks of 1 KB per phase (3 rows x 3 kcl x 4
    // quarters), 9 gload_lds per wave. dst is wave-uniform; lane l lands at
    // dst + l*16 -> px = 1 + q*16 + l/4, ci0 = (l%4)*8, matching xbf16 order.
    auto issue_phase = [&](int buf, int ph) {
        const int kc0 = ph * 3;
        #pragma unroll
        for (int i = 0; i < 9; ++i) {
            int c = wv * 9 + i;
            int r = c / 12, kcl = (c % 12) >> 2, q = c & 3;
            int hr = h - 1 + r;
            if (hr >= 0 && hr < 64) {
                const unsigned short* src = xbf16
                    + ((((size_t)(b * 64 + hr)) * 6 + (kc0 + kcl)) << 11)
                    + (q << 9) + lane * 8;
                unsigned short* dst = Asm + buf * 19008
                    + ((r * 3 + kcl) * 66 + 1) * 32 + q * 512;
                gload_lds16(src, dst);
            }
        }
    };

    // ---- B ring (5 slots, issue 4 ahead) / A ring (3 slots, issue 2 ahead)
    short8 Bb[5][3], Ab[3][4];
    auto loadB = [&](int t, int slot) {      // t in [0,54)
        int ph = t / 27, tt = t - ph * 27;
        int tap = tt / 3, kcl = tt - tap * 3;
        int s = tap * 6 + ph * 3 + kcl;
        #pragma unroll
        for (int nt = 0; nt < 3; ++nt)
            Bb[slot][nt] = *(const short8*)(wp + Bbase[nt] + s * (C_ * 32));
    };
    auto loadA = [&](int t, int slot) {      // t in [0,54)
        int ph = t / 27, tt = t - ph * 27;
        int tap = tt / 3, kcl = tt - tap * 3;
        int dh = tap / 3, dw = tap % 3 - 1;
        const short* As = (const short*)Asm + ph * 19008;
        int base = ((dh * 3 + kcl) * 66 + dw) * 32;
        #pragma unroll
        for (int mt = 0; mt < 4; ++mt)
            Ab[slot][mt] = *(const short8*)(As + base + Alds[mt]);
    };

    issue_phase(0, 0);                      // staging first (deepest latency)
    loadB(0, 0); loadB(1, 1); loadB(2, 2); loadB(3, 3);
    __syncthreads();                        // drains staging-0 (+B 0..3)
    issue_phase(1, 1);                      // in flight under phase-0 compute
    loadA(0, 0); loadA(1, 1);

    #pragma unroll
    for (int t = 0; t < 27; ++t) {
        loadB(t + 4, (t + 4) % 5);          // t=23..26 pre-issue phase-1 B
        if (t + 2 < 27) loadA(t + 2, (t + 2) % 3);
        #pragma unroll
        for (int mt = 0; mt < 4; ++mt)
            #pragma unroll
            for (int nt = 0; nt < 3; ++nt)
                acc[mt][nt] = __builtin_amdgcn_mfma_f32_16x16x32_bf16(
                    Ab[t % 3][mt], Bb[t % 5][nt], acc[mt][nt], 0, 0, 0);
    }

    __syncthreads();                        // buf1 staged (B 27..30 in regs)
    loadA(27, 0); loadA(28, 1);

    #pragma unroll
    for (int t = 27; t < 54; ++t) {
        if (t + 4 < 54) loadB(t + 4, (t + 4) % 5);
        if (t + 2 < 54) loadA(t + 2, (t + 2) % 3);
        #pragma unroll
        for (int mt = 0; mt < 4; ++mt)
            #pragma unroll
            for (int nt = 0; nt < 3; ++nt)
                acc[mt][nt] = __builtin_amdgcn_mfma_f32_16x16x32_bf16(
                    Ab[t % 3][mt], Bb[t % 5][nt], acc[mt][nt], 0, 0, 0);
    }

    // ---- epilogue
    #pragma unroll
    for (int nt = 0; nt < 3; ++nt) {
        const int co = n0 + nt * 16 + lo;
        const float fb = fusion_b[co];
        #pragma unroll
        for (int mt = 0; mt < 4; ++mt) {
            #pragma unroll
            for (int r = 0; r < 4; ++r) {
                const int px = mt * 16 + quad * 4 + r;
                out[((size_t)(b * 4096 + h * 64 + px)) * C_ + co] = acc[mt][nt][r] + fb;
            }
        }
    }
}

// ---------------------------------------------------------------------------
extern "C" void kernel_launch(void* const* d_in, const int* in_sizes, int n_in,
                              void* d_out, int out_size, void* d_ws, size_t ws_size,
                              hipStream_t stream) {
    const float* x        = (const float*)d_in[0];
    const float* conv1_w  = (const float*)d_in[1];
    const float* dc_w     = (const float*)d_in[2];
    const float* dc_b     = (const float*)d_in[3];
    const float* l1_w     = (const float*)d_in[4];
    const float* l1_b     = (const float*)d_in[5];
    const float* l2_w     = (const float*)d_in[6];
    const float* l2_b     = (const float*)d_in[7];
    const float* gk_w     = (const float*)d_in[8];
    const float* gk_b     = (const float*)d_in[9];
    const float* fusion_w = (const float*)d_in[10];
    const float* fusion_b = (const float*)d_in[11];
    float* out = (float*)d_out;

    char* ws = (char*)d_ws;
    float* w0p  = (float*)ws;                                   // 1,024 B
    float* cw_t = (float*)(ws + 1024);                          // 110,592 B
    unsigned short* Wl = (unsigned short*)(ws + 1024 + 110592); // 2,654,208 B
    unsigned short* xbf16 = (unsigned short*)(ws + 1024 + 110592 + 2654208); // 6,291,456 B

    hipLaunchKernelGGL(pre_kernel, dim3(566), dim3(256), 0, stream,
                       x, conv1_w, dc_w, w0p, cw_t, xbf16);
    hipLaunchKernelGGL(weff_kernel, dim3(B_ * C_), dim3(192), 0, stream,
                       cw_t, gk_w, gk_b, fusion_w, w0p, dc_b, l1_w, l1_b, l2_w, l2_b, Wl);
    hipLaunchKernelGGL(conv_kernel, dim3(256), dim3(256), 0, stream,
                       xbf16, Wl, fusion_b, out);
}